// Round 1
// baseline (821.018 us; speedup 1.0000x reference)
//
#include <hip/hip_runtime.h>
#include <math.h>

#define TPB 256
#define ROWS_PER_BLOCK 256
#define LDS_STRIDE 33   // pad 32-col chunk to 33 floats: banks (t+c)%32 -> conflict-free

__global__ __launch_bounds__(TPB, 4) void decoder_kernel(
    const float* __restrict__ feat,
    const float* __restrict__ W1, const float* __restrict__ g1, const float* __restrict__ b1,
    const float* __restrict__ W2, const float* __restrict__ g2, const float* __restrict__ b2,
    const float* __restrict__ W3, const float* __restrict__ b3,
    float* __restrict__ out, int N)
{
    __shared__ float xs[ROWS_PER_BLOCK * LDS_STRIDE];  // 33792 B

    const int t = threadIdx.x;
    const int row0 = blockIdx.x * ROWS_PER_BLOCK;
    const int myrow = row0 + t;

    float acc[32];
#pragma unroll
    for (int j = 0; j < 32; ++j) acc[j] = 0.f;

    // ---- Layer 1: x @ W1^T, streamed in 4 chunks of 32 columns ----
    for (int c0 = 0; c0 < 128; c0 += 32) {
        __syncthreads();  // previous chunk's reads done before overwrite
        // stage 256 rows x 32 cols, coalesced: 8 lanes cover one row's 128 B chunk
#pragma unroll
        for (int i = 0; i < 8; ++i) {
            const int r = (t >> 3) + i * 32;
            const int p = t & 7;
            int gr = row0 + r; if (gr >= N) gr = N - 1;   // safety clamp (N % 256 == 0 normally)
            const float4 v = *reinterpret_cast<const float4*>(
                feat + (size_t)gr * 128 + c0 + p * 4);
            const int l = r * LDS_STRIDE + p * 4;
            xs[l + 0] = v.x; xs[l + 1] = v.y; xs[l + 2] = v.z; xs[l + 3] = v.w;
        }
        __syncthreads();
        // each thread consumes its own row; W1 via wave-uniform (scalar-cache) loads
#pragma unroll
        for (int c = 0; c < 32; ++c) {
            const float xv = xs[t * LDS_STRIDE + c];
#pragma unroll
            for (int j = 0; j < 32; ++j)
                acc[j] = fmaf(xv, W1[j * 128 + c0 + c], acc[j]);
        }
    }

    // ---- LayerNorm(32) + leaky ----
    float m = 0.f;
#pragma unroll
    for (int j = 0; j < 32; ++j) m += acc[j];
    m *= (1.f / 32.f);
    float var = 0.f;
#pragma unroll
    for (int j = 0; j < 32; ++j) { const float d = acc[j] - m; var = fmaf(d, d, var); }
    var *= (1.f / 32.f);
    const float rs1 = rsqrtf(var + 1e-5f);

    float z[32];
#pragma unroll
    for (int j = 0; j < 32; ++j) {
        float y = (acc[j] - m) * rs1 * g1[j] + b1[j];
        z[j] = (y >= 0.f) ? y : 0.1f * y;
    }

    // ---- Layer 2: [32] -> [16] ----
    float a2[16];
#pragma unroll
    for (int k = 0; k < 16; ++k) a2[k] = 0.f;
#pragma unroll
    for (int j = 0; j < 32; ++j) {
        const float zj = z[j];
#pragma unroll
        for (int k = 0; k < 16; ++k)
            a2[k] = fmaf(zj, W2[k * 32 + j], a2[k]);
    }

    // ---- LayerNorm(16) + leaky ----
    float m2 = 0.f;
#pragma unroll
    for (int k = 0; k < 16; ++k) m2 += a2[k];
    m2 *= (1.f / 16.f);
    float v2 = 0.f;
#pragma unroll
    for (int k = 0; k < 16; ++k) { const float d = a2[k] - m2; v2 = fmaf(d, d, v2); }
    v2 *= (1.f / 16.f);
    const float rs2 = rsqrtf(v2 + 1e-5f);

    float z2[16];
#pragma unroll
    for (int k = 0; k < 16; ++k) {
        float y = (a2[k] - m2) * rs2 * g2[k] + b2[k];
        z2[k] = (y >= 0.f) ? y : 0.1f * y;
    }

    // ---- Layer 3: [16] -> [3] + bias ----
    float o[3];
#pragma unroll
    for (int q = 0; q < 3; ++q) {
        float s = b3[q];
#pragma unroll
        for (int k = 0; k < 16; ++k)
            s = fmaf(z2[k], W3[q * 16 + k], s);
        o[q] = s;
    }

    // ---- normalize: x / max(||x||, 1e-12) ----
    const float nrm = sqrtf(o[0] * o[0] + o[1] * o[1] + o[2] * o[2]);
    const float inv = 1.f / fmaxf(nrm, 1e-12f);

    if (myrow < N) {
        out[(size_t)myrow * 3 + 0] = o[0] * inv;
        out[(size_t)myrow * 3 + 1] = o[1] * inv;
        out[(size_t)myrow * 3 + 2] = o[2] * inv;
    }
}

extern "C" void kernel_launch(void* const* d_in, const int* in_sizes, int n_in,
                              void* d_out, int out_size, void* d_ws, size_t ws_size,
                              hipStream_t stream) {
    const float* feat = (const float*)d_in[0];
    const float* W1   = (const float*)d_in[1];
    const float* g1   = (const float*)d_in[2];
    const float* b1   = (const float*)d_in[3];
    const float* W2   = (const float*)d_in[4];
    const float* g2   = (const float*)d_in[5];
    const float* b2   = (const float*)d_in[6];
    const float* W3   = (const float*)d_in[7];
    const float* b3   = (const float*)d_in[8];
    float* out = (float*)d_out;

    const int N = in_sizes[0] / 128;
    const int grid = (N + ROWS_PER_BLOCK - 1) / ROWS_PER_BLOCK;

    decoder_kernel<<<grid, TPB, 0, stream>>>(feat, W1, g1, b1, W2, g2, b2, W3, b3, out, N);
}

// Round 2
// 218.256 us; speedup vs baseline: 3.7617x; 3.7617x over previous
//
#include <hip/hip_runtime.h>
#include <math.h>

#define TPB 256
#define ROWS_PER_BLOCK 256
#define LDS_STRIDE 33   // odd stride: (t + c) % 32 covers all banks -> 2-way max (free)

__global__ __launch_bounds__(TPB, 4) void decoder_kernel(
    const float* __restrict__ feat,
    const float* __restrict__ W1, const float* __restrict__ g1, const float* __restrict__ b1,
    const float* __restrict__ W2, const float* __restrict__ g2, const float* __restrict__ b2,
    const float* __restrict__ W3, const float* __restrict__ b3,
    float* __restrict__ out, int N)
{
    __shared__ float xs[ROWS_PER_BLOCK * LDS_STRIDE];  // 33792 B -> 4 blocks/CU

    const int t = threadIdx.x;
    const int row0 = blockIdx.x * ROWS_PER_BLOCK;
    const int myrow = row0 + t;

    float acc[32];
#pragma unroll
    for (int j = 0; j < 32; ++j) acc[j] = 0.f;

    // ---- Layer 1: x @ W1^T, streamed in 4 chunks of 32 columns ----
    for (int c0 = 0; c0 < 128; c0 += 32) {
        __syncthreads();  // previous chunk's xr reads done before overwrite
        // stage 256 rows x 32 cols, coalesced: 8 lanes cover one row's 128 B slice
#pragma unroll
        for (int i = 0; i < 8; ++i) {
            const int r = (t >> 3) + i * 32;
            const int p = t & 7;
            int gr = row0 + r; if (gr >= N) gr = N - 1;
            const float4 v = *reinterpret_cast<const float4*>(
                feat + (size_t)gr * 128 + c0 + p * 4);
            const int l = r * LDS_STRIDE + p * 4;
            xs[l + 0] = v.x; xs[l + 1] = v.y; xs[l + 2] = v.z; xs[l + 3] = v.w;
        }
        __syncthreads();

        // hoist this thread's 32 x-values into VGPRs (reused for all 32 outputs)
        float xr[32];
#pragma unroll
        for (int c = 0; c < 32; ++c) xr[c] = xs[t * LDS_STRIDE + c];

        // j-outer: W1 row j slice [c0..c0+31] is CONTIGUOUS -> s_load_dwordx16 pairs,
        // each v_fmac reads the weight straight from an SGPR.
#pragma unroll
        for (int j = 0; j < 32; ++j) {
            const float* __restrict__ wrow = W1 + j * 128 + c0;
            float s = acc[j];
#pragma unroll
            for (int c = 0; c < 32; ++c)
                s = fmaf(xr[c], wrow[c], s);
            acc[j] = s;
        }
    }

    // ---- LayerNorm(32) + leaky ----
    float m = 0.f;
#pragma unroll
    for (int j = 0; j < 32; ++j) m += acc[j];
    m *= (1.f / 32.f);
    float var = 0.f;
#pragma unroll
    for (int j = 0; j < 32; ++j) { const float d = acc[j] - m; var = fmaf(d, d, var); }
    var *= (1.f / 32.f);
    const float rs1 = rsqrtf(var + 1e-5f);

    float z[32];
#pragma unroll
    for (int j = 0; j < 32; ++j) {
        float y = (acc[j] - m) * rs1 * g1[j] + b1[j];
        z[j] = (y >= 0.f) ? y : 0.1f * y;
    }

    // ---- Layer 2: [32] -> [16], k-outer so W2 row k is contiguous ----
    float a2[16];
#pragma unroll
    for (int k = 0; k < 16; ++k) {
        const float* __restrict__ wrow = W2 + k * 32;
        float s = 0.f;
#pragma unroll
        for (int j = 0; j < 32; ++j)
            s = fmaf(z[j], wrow[j], s);
        a2[k] = s;
    }

    // ---- LayerNorm(16) + leaky ----
    float m2 = 0.f;
#pragma unroll
    for (int k = 0; k < 16; ++k) m2 += a2[k];
    m2 *= (1.f / 16.f);
    float v2 = 0.f;
#pragma unroll
    for (int k = 0; k < 16; ++k) { const float d = a2[k] - m2; v2 = fmaf(d, d, v2); }
    v2 *= (1.f / 16.f);
    const float rs2 = rsqrtf(v2 + 1e-5f);

    float z2[16];
#pragma unroll
    for (int k = 0; k < 16; ++k) {
        float y = (a2[k] - m2) * rs2 * g2[k] + b2[k];
        z2[k] = (y >= 0.f) ? y : 0.1f * y;
    }

    // ---- Layer 3: [16] -> [3] + bias (W3 rows contiguous) ----
    float o[3];
#pragma unroll
    for (int q = 0; q < 3; ++q) {
        const float* __restrict__ wrow = W3 + q * 16;
        float s = b3[q];
#pragma unroll
        for (int k = 0; k < 16; ++k)
            s = fmaf(z2[k], wrow[k], s);
        o[q] = s;
    }

    // ---- normalize: x / max(||x||, 1e-12) ----
    const float nrm = sqrtf(o[0] * o[0] + o[1] * o[1] + o[2] * o[2]);
    const float inv = 1.f / fmaxf(nrm, 1e-12f);

    if (myrow < N) {
        out[(size_t)myrow * 3 + 0] = o[0] * inv;
        out[(size_t)myrow * 3 + 1] = o[1] * inv;
        out[(size_t)myrow * 3 + 2] = o[2] * inv;
    }
}

extern "C" void kernel_launch(void* const* d_in, const int* in_sizes, int n_in,
                              void* d_out, int out_size, void* d_ws, size_t ws_size,
                              hipStream_t stream) {
    const float* feat = (const float*)d_in[0];
    const float* W1   = (const float*)d_in[1];
    const float* g1   = (const float*)d_in[2];
    const float* b1   = (const float*)d_in[3];
    const float* W2   = (const float*)d_in[4];
    const float* g2   = (const float*)d_in[5];
    const float* b2   = (const float*)d_in[6];
    const float* W3   = (const float*)d_in[7];
    const float* b3   = (const float*)d_in[8];
    float* out = (float*)d_out;

    const int N = in_sizes[0] / 128;
    const int grid = (N + ROWS_PER_BLOCK - 1) / ROWS_PER_BLOCK;

    decoder_kernel<<<grid, TPB, 0, stream>>>(feat, W1, g1, b1, W2, g2, b2, W3, b3, out, N);
}